// Round 5
// baseline (669.190 us; speedup 1.0000x reference)
//
#include <hip/hip_runtime.h>

// LSTM predictor: B=1024, T=1024, H=51, input=1. fp32 VALU-bound recurrence.
//
// Rounds 1-4 established: a single wave cannot hold 204 W_hh weights
// VALU-readable (arch-VGPR allocator caps ~130; AGPR "residency" costs a
// v_accvgpr_read per use -- plain VALU has NO AGPR-source encoding).
// Restructure instead: one block (4 waves) per batch element, each wave
// owns a 13-wide k-slice of the reduction -> 52 resident weights/lane,
// well inside the allocator's comfort zone. h is shared via LDS broadcast
// reads (DS pipe, not VALU). Activations are split across waves by gate
// (wave-uniform sigmoid/tanh branch). The c/h update runs on one "owner"
// wave, hashed by blockIdx so owner waves spread across SIMDs.
// 3 barriers/step; 4 blocks/CU hide each other's barrier/LDS latency.

#define HID 51
#define SEQ_T 1024
#define NK 13  // k-slice width per wave; wave w covers k in [13w, 13w+12]

__device__ __forceinline__ float lane_bcast(float v, int lane) {
    return __int_as_float(__builtin_amdgcn_readlane(__float_as_int(v), lane));
}

// sigmoid(x) = 1 / (1 + 2^(-x*log2e))
__device__ __forceinline__ float fast_sigmoid(float x) {
    float e = __builtin_amdgcn_exp2f(x * -1.44269504088896340736f);
    return __builtin_amdgcn_rcpf(1.0f + e);
}

// tanh(x) = 1 - 2/(2^(2x*log2e) + 1)
__device__ __forceinline__ float fast_tanh(float x) {
    float e = __builtin_amdgcn_exp2f(x * 2.88539008177792681472f);
    return 1.0f - 2.0f * __builtin_amdgcn_rcpf(e + 1.0f);
}

__global__ __launch_bounds__(256) void lstm_quad_kernel(
    const float* __restrict__ x,      // [B, T]
    const float* __restrict__ W_ih,   // [4H, 1]
    const float* __restrict__ W_hh,   // [4H, H]
    const float* __restrict__ b_ih,   // [4H]
    const float* __restrict__ b_hh,   // [4H]
    const float* __restrict__ fc_w,   // [1, H]
    const float* __restrict__ fc_b,   // [1]
    float* __restrict__ out)          // [B, T]
{
    const int b = blockIdx.x;
    const int tid = threadIdx.x;
    const int w = tid >> 6;   // wave slot: k-slice role AND gate role
    const int l = tid & 63;
    const int K0 = NK * w;
    // c/h-update owner wave, hashed so owners spread over SIMDs even if
    // resident blocks share low or high blockIdx bits.
    const int mix = b ^ (b >> 2) ^ (b >> 4) ^ (b >> 6) ^ (b >> 8);
    const bool own = (w == (mix & 3));

    __shared__ float hbuf[64];         // h[k], k<51 valid, rest 0
    __shared__ float part[4][4][64];   // [src wave][gate][lane]
    __shared__ float actbuf[4][64];    // [gate][lane]
    __shared__ float pbuf[64][65];     // fc staging, stride-65 conflict-free

    // ---- per-lane weights: my k-slice of all 4 gates (52 regs) ----
    float wq0[NK], wq1[NK], wq2[NK], wq3[NK];
#pragma unroll
    for (int j = 0; j < NK; ++j) {
        int k = K0 + j;
        bool v = (l < HID) && (k < HID);  // wave3 j=12 -> k=51: pad 0
        wq0[j] = v ? W_hh[(0 * HID + l) * HID + k] : 0.f;
        wq1[j] = v ? W_hh[(1 * HID + l) * HID + k] : 0.f;
        wq2[j] = v ? W_hh[(2 * HID + l) * HID + k] : 0.f;
        wq3[j] = v ? W_hh[(3 * HID + l) * HID + k] : 0.f;
    }
    const int g = w;  // gate role (i,f,g,o = 0,1,2,3)
    const float bg_ = (l < HID) ? b_ih[g * HID + l] + b_hh[g * HID + l] : 0.f;
    const float wx_ = (l < HID) ? W_ih[g * HID + l] : 0.f;
    const float fcw = (own && l < HID) ? fc_w[l] : 0.f;
    const float fcb = fc_b[0];
    float c = 0.f;

    if (tid < 64) hbuf[tid] = 0.f;
    __syncthreads();

#pragma unroll 1
    for (int t0 = 0; t0 < SEQ_T; t0 += 64) {
        const float xv = x[b * SEQ_T + t0 + l];  // all waves: same chunk
#pragma unroll 1
        for (int i = 0; i < 64; ++i) {
            // ---- A: partial gate sums over my k-slice ----
            float p0 = 0.f, p1 = 0.f, p2 = 0.f, p3 = 0.f;
#pragma unroll
            for (int j = 0; j < NK; ++j) {
                const float hk = hbuf[K0 + j];  // uniform addr -> broadcast
                p0 = fmaf(hk, wq0[j], p0);
                p1 = fmaf(hk, wq1[j], p1);
                p2 = fmaf(hk, wq2[j], p2);
                p3 = fmaf(hk, wq3[j], p3);
            }
            part[w][0][l] = p0; part[w][1][l] = p1;
            part[w][2][l] = p2; part[w][3][l] = p3;
            __syncthreads();

            // ---- B: gather my gate, activation (wave-uniform branch) ----
            const float xt = lane_bcast(xv, i);
            float s = part[0][g][l] + part[1][g][l] + part[2][g][l]
                    + part[3][g][l];
            s += fmaf(xt, wx_, bg_);
            const float a = (g == 2) ? fast_tanh(s) : fast_sigmoid(s);
            actbuf[g][l] = a;
            __syncthreads();

            // ---- C: owner wave updates c, h; publishes h ----
            if (own) {
                const float ig = actbuf[0][l], fg = actbuf[1][l];
                const float gg = actbuf[2][l], og = actbuf[3][l];
                c = fmaf(fg, c, ig * gg);
                const float hn = og * fast_tanh(c);
                hbuf[l] = hn;            // lanes>=51 compute hn=0 naturally
                pbuf[l][i] = hn * fcw;
            }
            __syncthreads();
        }
        // fc output for this 64-step chunk (owner only; pbuf is owner-private)
        if (own) {
            float s2 = 0.f;
#pragma unroll
            for (int k = 0; k < HID; ++k) s2 += pbuf[k][l];
            out[b * SEQ_T + t0 + l] = s2 + fcb;
        }
    }
}

extern "C" void kernel_launch(void* const* d_in, const int* in_sizes, int n_in,
                              void* d_out, int out_size, void* d_ws, size_t ws_size,
                              hipStream_t stream) {
    (void)in_sizes; (void)n_in; (void)d_ws; (void)ws_size; (void)out_size;
    const float* x    = (const float*)d_in[0];
    const float* W_ih = (const float*)d_in[1];
    const float* W_hh = (const float*)d_in[2];
    const float* b_ih = (const float*)d_in[3];
    const float* b_hh = (const float*)d_in[4];
    const float* fc_w = (const float*)d_in[5];
    const float* fc_b = (const float*)d_in[6];
    float* out = (float*)d_out;

    lstm_quad_kernel<<<dim3(1024), dim3(256), 0, stream>>>(
        x, W_ih, W_hh, b_ih, b_hh, fc_w, fc_b, out);
}

// Round 6
// 515.933 us; speedup vs baseline: 1.2970x; 1.2970x over previous
//
#include <hip/hip_runtime.h>

// LSTM predictor: B=1024, T=1024, H=51, input=1. Sequential recurrence,
// VALU-bound. Rounds 1-5 established the hard constraint: a wave gets only
// ~110-130 VALU-readable (arch) VGPRs; beyond that the allocator parks
// values in AGPRs, and plain VALU has NO AGPR-source encoding (round-4
// compile error) -> v_accvgpr_read per use, ~2x step cost.
//
// This round: v_dot2_f32_f16 (2 MACs/instr, f16 operands, fp32 accum).
//  - 2 waves/block, block=batch. wave0: gates i,f; wave1: g,o.
//  - 51 packed-pair weight regs per gate-pair wave (fits the ~110 budget).
//  - ONE barrier/step: activation exchange via parity double-buffered LDS;
//    both waves compute the c/h update redundantly (bit-identical replicas)
//    and repack their OWN f16 h-copy in a per-wave LDS strip (no cross-wave
//    h dependency, no second barrier).
//  - fc output staged by wave0 in stride-65 LDS, reduced every 64 steps.

#define HID 51
#define SEQ_T 1024
#define NPAIR 26  // k-pairs (k=51 padded with zero)

typedef _Float16 f16;
typedef __attribute__((ext_vector_type(2))) _Float16 half2_t;

static __device__ __forceinline__ float lane_bcast(float v, int lane) {
    return __int_as_float(__builtin_amdgcn_readlane(__float_as_int(v), lane));
}
static __device__ __forceinline__ float fast_sigmoid(float x) {
    float e = __builtin_amdgcn_exp2f(x * -1.44269504088896340736f);
    return __builtin_amdgcn_rcpf(1.0f + e);
}
static __device__ __forceinline__ float fast_tanh(float x) {
    float e = __builtin_amdgcn_exp2f(x * 2.88539008177792681472f);
    return 1.0f - 2.0f * __builtin_amdgcn_rcpf(e + 1.0f);
}
static __device__ __forceinline__ float fdot2(unsigned int hp, unsigned int wp,
                                              float acc) {
    return __builtin_amdgcn_fdot2(__builtin_bit_cast(half2_t, hp),
                                  __builtin_bit_cast(half2_t, wp), acc, false);
}

__global__ __launch_bounds__(128)
__attribute__((amdgpu_waves_per_eu(2, 2)))
void lstm_duo_kernel(
    const float* __restrict__ x,      // [B, T]
    const float* __restrict__ W_ih,   // [4H, 1]
    const float* __restrict__ W_hh,   // [4H, H]
    const float* __restrict__ b_ih,   // [4H]
    const float* __restrict__ b_hh,   // [4H]
    const float* __restrict__ fc_w,   // [1, H]
    const float* __restrict__ fc_b,   // [1]
    float* __restrict__ out)          // [B, T]
{
    const int b = blockIdx.x;
    const int tid = threadIdx.x;
    const int w = tid >> 6;  // 0: gates {i,f}; 1: gates {g,o}
    const int l = tid & 63;
    const bool act = (l < HID);

    __shared__ __align__(16) unsigned int hpk[2][32];  // per-wave f16 h (64 ea)
    __shared__ float2 actx[2][2][64];                  // [parity][wave][lane]
    __shared__ float pbuf[64][65];                     // fc staging (wave0)

    const int gA = 2 * w;      // wave0: 0=i, wave1: 2=g
    const int gB = 2 * w + 1;  // wave0: 1=f, wave1: 3=o

    // ---- pack this wave's 2 gate-rows of W_hh into f16 pairs (52 regs) ----
    unsigned int wA[NPAIR], wB[NPAIR];
#pragma unroll
    for (int p = 0; p < NPAIR; ++p) {
        float a0 = 0.f, a1 = 0.f, b0 = 0.f, b1 = 0.f;
        if (act) {
            const int k0 = 2 * p, k1 = 2 * p + 1;
            a0 = W_hh[(gA * HID + l) * HID + k0];
            b0 = W_hh[(gB * HID + l) * HID + k0];
            if (k1 < HID) {
                a1 = W_hh[(gA * HID + l) * HID + k1];
                b1 = W_hh[(gB * HID + l) * HID + k1];
            }
        }
        half2_t pa = { (f16)a0, (f16)a1 };
        half2_t pb = { (f16)b0, (f16)b1 };
        wA[p] = __builtin_bit_cast(unsigned int, pa);
        wB[p] = __builtin_bit_cast(unsigned int, pb);
        asm volatile("" : "+v"(wA[p]), "+v"(wB[p]));
    }
    float bA = 0.f, bB = 0.f, wxA = 0.f, wxB = 0.f, fcw = 0.f;
    if (act) {
        bA = b_ih[gA * HID + l] + b_hh[gA * HID + l];
        bB = b_ih[gB * HID + l] + b_hh[gB * HID + l];
        wxA = W_ih[gA * HID + l];
        wxB = W_ih[gB * HID + l];
        fcw = fc_w[l];
    }
    const float fcb = fc_b[0];
    float c = 0.f;

    // zero own h replica (h0 = 0); same-wave write->read needs no barrier
    ((f16*)hpk[w])[l] = (f16)0.f;

#pragma unroll 1
    for (int t0 = 0; t0 < SEQ_T; t0 += 64) {
        const float xv = x[b * SEQ_T + t0 + l];  // 64 steps of input
#pragma unroll 1
        for (int i = 0; i < 64; ++i) {
            const int par = i & 1;

            // ---- A: load own h replica (7 uniform b128 reads -> 28 pairs) --
            unsigned int hq[28];
#pragma unroll
            for (int j = 0; j < 7; ++j) {
                uint4 q = ((const uint4*)hpk[w])[j];
                hq[4 * j + 0] = q.x; hq[4 * j + 1] = q.y;
                hq[4 * j + 2] = q.z; hq[4 * j + 3] = q.w;
            }

            // ---- gate sums: 52 fdot2 over 26 pairs, 4 indep chains ----
            const float xt = lane_bcast(xv, i);
            float sA0 = fmaf(xt, wxA, bA), sA1 = 0.f;
            float sB0 = fmaf(xt, wxB, bB), sB1 = 0.f;
#pragma unroll
            for (int p = 0; p < NPAIR; p += 2) {
                sA0 = fdot2(hq[p], wA[p], sA0);
                sB0 = fdot2(hq[p], wB[p], sB0);
                sA1 = fdot2(hq[p + 1], wA[p + 1], sA1);
                sB1 = fdot2(hq[p + 1], wB[p + 1], sB1);
            }
            const float sA = sA0 + sA1;
            const float sB = sB0 + sB1;

            // ---- activations (wave-uniform branch) + exchange ----
            float aA, aB;
            if (w == 0) { aA = fast_sigmoid(sA); aB = fast_sigmoid(sB); }
            else        { aA = fast_tanh(sA);    aB = fast_sigmoid(sB); }
            actx[par][w][l] = make_float2(aA, aB);
            __syncthreads();  // the ONE barrier per step
            const float2 other = actx[par][1 - w][l];

            float ig, fg, gg, og;
            if (w == 0) { ig = aA;      fg = aB;      gg = other.x; og = other.y; }
            else        { ig = other.x; fg = other.y; gg = aA;      og = aB; }

            // ---- redundant c/h update (replicas bit-identical) ----
            c = fmaf(fg, c, ig * gg);
            const float hn = og * fast_tanh(c);
            // repack own h replica; lanes>=51 have hn==0 (zero params) so all
            // 64 f16 slots (incl. pad pairs) are rewritten each step.
            ((f16*)hpk[w])[l] = (f16)hn;

            if (w == 0) pbuf[l][i] = hn * fcw;  // fc staging (stride-65)
        }
        if (w == 0) {
            float s2 = 0.f;
#pragma unroll
            for (int k = 0; k < HID; ++k) s2 += pbuf[k][l];
            out[b * SEQ_T + t0 + l] = s2 + fcb;  // coalesced 64-chunk
        }
    }
}

extern "C" void kernel_launch(void* const* d_in, const int* in_sizes, int n_in,
                              void* d_out, int out_size, void* d_ws, size_t ws_size,
                              hipStream_t stream) {
    (void)in_sizes; (void)n_in; (void)d_ws; (void)ws_size; (void)out_size;
    const float* x    = (const float*)d_in[0];
    const float* W_ih = (const float*)d_in[1];
    const float* W_hh = (const float*)d_in[2];
    const float* b_ih = (const float*)d_in[3];
    const float* b_hh = (const float*)d_in[4];
    const float* fc_w = (const float*)d_in[5];
    const float* fc_b = (const float*)d_in[6];
    float* out = (float*)d_out;

    lstm_duo_kernel<<<dim3(1024), dim3(128), 0, stream>>>(
        x, W_ih, W_hh, b_ih, b_hh, fc_w, fc_b, out);
}